// Round 5
// baseline (111.204 us; speedup 1.0000x reference)
//
#include <hip/hip_runtime.h>
#include <hip/hip_bf16.h>
#include <stdint.h>
#include <stddef.h>

#define NS 8192
#define NT 8192
#define DD 512
#define INV_DNT (1.0f / ((float)DD * (float)NT))
#define INV_NT  (1.0f / (float)NT)

typedef __attribute__((ext_vector_type(8))) short short8;
typedef __attribute__((ext_vector_type(4))) float f32x4;

// ---- workspace layout (bytes) ----
#define WS_A    ((size_t)0)                    // NS*DD bf16
#define WS_B    (WS_A + (size_t)NS * DD * 2)   // NT*DD bf16
#define WS_SQS  (WS_B + (size_t)NT * DD * 2)   // NS f32 raw row sumsq
#define WS_SQT  (WS_SQS + (size_t)NS * 4)      // NT f32

__device__ __forceinline__ void gload16(const void* g, void* l) {
  __builtin_amdgcn_global_load_lds(
      (const __attribute__((address_space(1))) unsigned int*)g,
      (__attribute__((address_space(3))) unsigned int*)l, 16, 0, 0);
}

// ============================================================================
// prep: streaming fp32->bf16 convert + raw row sum-of-squares.
// ============================================================================
__global__ __launch_bounds__(256) void prep_kernel(
    const float* __restrict__ src, const float* __restrict__ tgt,
    char* __restrict__ ws) {
  const int tid = threadIdx.x, wid = tid >> 6, lane = tid & 63;
  __hip_bfloat16* Ab = (__hip_bfloat16*)(ws + WS_A);
  __hip_bfloat16* Bb = (__hip_bfloat16*)(ws + WS_B);
  float* sqs = (float*)(ws + WS_SQS);
  float* sqt = (float*)(ws + WS_SQT);

#pragma unroll
  for (int it = 0; it < 4; ++it) {
    const int row = blockIdx.x * 4 + wid + it * 4096;   // 0..16383
    const bool isT = row >= NS;
    const int r = isT ? row - NS : row;
    const float* in = (isT ? tgt : src) + (size_t)r * DD;
    const float4* rp = (const float4*)in;
    float4 v0 = rp[lane * 2], v1 = rp[lane * 2 + 1];
    float x[8] = {v0.x, v0.y, v0.z, v0.w, v1.x, v1.y, v1.z, v1.w};
    float ss = 0.f;
#pragma unroll
    for (int j = 0; j < 8; ++j) ss += x[j] * x[j];
    union { short8 s; __hip_bfloat16 h[8]; } u;
#pragma unroll
    for (int j = 0; j < 8; ++j) u.h[j] = __float2bfloat16(x[j]);
    *(short8*)((isT ? Bb : Ab) + (size_t)r * DD + lane * 8) = u.s;
#pragma unroll
    for (int off = 32; off >= 1; off >>= 1) ss += __shfl_xor(ss, off, 64);
    if (lane == 0) (isT ? sqt : sqs)[r] = ss;
  }
}

// ============================================================================
// gram: 256x256 tile, BK=64, 8 waves (2M x 4N), read-minimal (kk,m-half)
// phases (24 ds_read_b128 / wave / K-tile).  m201 TWO-BARRIER phase shape:
//   {ds_reads; stages; sched_barrier; s_barrier; setprio; MFMA (compiler
//    fine-grained lgkm waits); setprio; [VM gate]; s_barrier}
// Staging units/VM gates identical to r4 (proven): {Ph1:B23(t+1),
// Ph2:A02(t+1), Ph3:A13(t+1), Ph4:B01(t+2)}, VM4 at end-Ph1/Ph4.
// Swizzle: physical byte = logical ^ ((row&7)<<4) (involution, rows 128B).
// ============================================================================
__global__ __launch_bounds__(512, 2) void gram_kernel(
    const char* __restrict__ ws, const int* __restrict__ ssec,
    const int* __restrict__ tsec, float* __restrict__ out) {
  __shared__ __align__(16) char lds[2][65536];   // [buf][A 32KB | B 32KB]

  const float* sqs = (const float*)(ws + WS_SQS);
  const float* sqt = (const float*)(ws + WS_SQT);

  // L2-friendly map: XCD x owns m_blks [4x,4x+4); within, 4m x 8n chunks.
  const int lin = blockIdx.x;
  const int xcd = lin & 7, i = lin >> 3;
  const int nc = i >> 5, r_ = i & 31;
  const int m_blk = xcd * 4 + (r_ & 3);
  const int n_blk = nc * 8 + (r_ >> 2);
  const int rowA = m_blk * 256, rowB = n_blk * 256;

  const int tid = threadIdx.x, wid = tid >> 6, lane = tid & 63;
  const int wrM = wid >> 2, wcN = wid & 3;
  const int q = lane & 15, h = lane >> 4;

  // ---- staging: 8 units (u>>2: 0=A,1=B; u&3: 64-row range). 1 gload16/wave.
  const char* srcP[8];
  int dstO[8];
#pragma unroll
  for (int u = 0; u < 8; ++u) {
    const int X = u >> 2, ur = u & 3;
    const int dst = X * 32768 + (ur * 64 + wid * 8) * 128;  // wave-uniform
    dstO[u] = dst;
    const int po = (ur * 64 + wid * 8) * 128 + lane * 16;   // phys byte in region
    const int row_p = po >> 7;
    const int bl = (po & 127) ^ ((row_p & 7) << 4);         // logical byte in row
    srcP[u] = ws + (X ? WS_B : WS_A) +
              (size_t)((X ? rowB : rowA) + row_p) * (DD * 2) + bl;
  }

#define STG(u, T) gload16(srcP[u] + (size_t)(T) * 128, &lds[(T) & 1][dstO[u]]);

  // ---- read-side fragment offsets (physical = logical ^ ((row&7)<<4)) ----
  const int swz = (q & 7) << 4;
  const int colx[2] = {(h * 16) ^ swz, (64 + h * 16) ^ swz};
  const int aBase = (wrM * 128 + q) * 128;
  const int bBase = 32768 + (wcN * 64 + q) * 128;

  f32x4 acc[8][4];
#pragma unroll
  for (int mi = 0; mi < 8; ++mi)
#pragma unroll
    for (int ni = 0; ni < 4; ++ni) acc[mi][ni] = (f32x4){0.f, 0.f, 0.f, 0.f};

  short8 bf[4], af[4];

#define VM4 asm volatile("s_waitcnt vmcnt(4)" ::: "memory")
#define VM2 asm volatile("s_waitcnt vmcnt(2)" ::: "memory")
#define VM0 asm volatile("s_waitcnt vmcnt(0)" ::: "memory")
#define VMNONE ((void)0)

  // PHASE (two-barrier m201 shape): reads; stages; SB0; BAR; MFMA; VM; BAR.
#define PHASE(TC, KK, MH, STGBLK, VMC)                                        \
  {                                                                           \
    const char* Lb = &lds[(TC) & 1][0];                                       \
    if ((MH) == 0) {                                                          \
      _Pragma("unroll") for (int ni = 0; ni < 4; ++ni)                        \
          bf[ni] = *(const short8*)(Lb + bBase + ni * 2048 + colx[KK]);       \
    }                                                                         \
    _Pragma("unroll") for (int mi = 0; mi < 4; ++mi)                          \
        af[mi] = *(const short8*)(Lb + aBase + ((MH)*4 + mi) * 2048 + colx[KK]);\
    STGBLK;                                                                   \
    __builtin_amdgcn_sched_barrier(0);                                        \
    __builtin_amdgcn_s_barrier();                                             \
    __builtin_amdgcn_s_setprio(1);                                            \
    _Pragma("unroll") for (int mi = 0; mi < 4; ++mi)                          \
      _Pragma("unroll") for (int ni = 0; ni < 4; ++ni)                        \
        acc[(MH)*4 + mi][ni] = __builtin_amdgcn_mfma_f32_16x16x32_bf16(       \
            af[mi], bf[ni], acc[(MH)*4 + mi][ni], 0, 0, 0);                   \
    __builtin_amdgcn_s_setprio(0);                                            \
    VMC;                                                                      \
    __builtin_amdgcn_s_barrier();                                             \
  }

  // ---- prologue: B(0) all, A02(0), A13(0), B01(1); retire first 6 ----
  STG(4, 0) STG(5, 0) STG(6, 0) STG(7, 0)
  STG(0, 0) STG(2, 0) STG(1, 0) STG(3, 0)
  STG(4, 1) STG(5, 1)
  VM4;
  __builtin_amdgcn_s_barrier();

#pragma unroll
  for (int t = 0; t < 6; ++t) {
    PHASE(t, 0, 0, { STG(6, t + 1) STG(7, t + 1) }, VM4)   // B23(t+1)
    PHASE(t, 0, 1, { STG(0, t + 1) STG(2, t + 1) }, VMNONE)// A02(t+1)
    PHASE(t, 1, 0, { STG(1, t + 1) STG(3, t + 1) }, VMNONE)// A13(t+1)
    PHASE(t, 1, 1, { STG(4, t + 2) STG(5, t + 2) }, VM4)   // B01(t+2)
  }
  // t = 6: last stages (units of tile 7); B01(8) suppressed
  PHASE(6, 0, 0, { STG(6, 7) STG(7, 7) }, VM4)
  PHASE(6, 0, 1, { STG(0, 7) STG(2, 7) }, VMNONE)
  PHASE(6, 1, 0, { STG(1, 7) STG(3, 7) }, VMNONE)
  PHASE(6, 1, 1, {}, VM2)
  // t = 7: drain
  PHASE(7, 0, 0, {}, VM0)
  PHASE(7, 0, 1, {}, VMNONE)
  PHASE(7, 1, 0, {}, VMNONE)
  PHASE(7, 1, 1, {}, VMNONE)
#undef PHASE
#undef STG

  // ---- epilogue: loss_s (same-sec sum of d2) + loss_c (hinge, rare) ----
  // C/D layout: col = q (target), row = h*4 + j (source)
  float sqc[4];
  int tc[4];
#pragma unroll
  for (int ni = 0; ni < 4; ++ni) {
    const int c = rowB + wcN * 64 + ni * 16 + q;
    sqc[ni] = sqt[c];
    tc[ni] = tsec[c];
  }
  const int rbase = rowA + wrM * 128;

  __syncthreads();                        // all tile reads done; reuse LDS
  float* lsr = (float*)&lds[0][0];        // [8 waves][4 h][32 (mi*4+j)]

#pragma unroll
  for (int mi = 0; mi < 8; ++mi) {
    const int r0 = rbase + mi * 16 + h * 4;
    const float4 s4 = *(const float4*)&sqs[r0];
    const int4 c4 = *(const int4*)&ssec[r0];
    const float sq4[4] = {s4.x, s4.y, s4.z, s4.w};
    const int sc4[4] = {c4.x, c4.y, c4.z, c4.w};
    float l[4] = {0.f, 0.f, 0.f, 0.f};
#pragma unroll
    for (int ni = 0; ni < 4; ++ni) {
#pragma unroll
      for (int j = 0; j < 4; ++j) {
        const float g = acc[mi][ni][j];
        const float d2r = sq4[j] + sqc[ni] - 2.f * g;
        if (sc4[j] == tc[ni]) {
          l[j] += fmaxf(d2r, 0.f);
        } else if (d2r < 128.f) {          // margin^2 * D; hinge (rare)
          const float d = sqrtf(fmaxf(d2r, 0.f) * (1.f / (float)DD));
          const float hh = 0.5f - d;
          atomicAdd(&out[NS + r0 + j], hh * hh * INV_NT);
        }
      }
    }
#pragma unroll
    for (int j = 0; j < 4; ++j) {
      float v = l[j];
      v += __shfl_xor(v, 1, 64);
      v += __shfl_xor(v, 2, 64);
      v += __shfl_xor(v, 4, 64);
      v += __shfl_xor(v, 8, 64);
      l[j] = v;
    }
    if (q < 4) {
      const float sv = (q == 0) ? l[0] : (q == 1) ? l[1] : (q == 2) ? l[2] : l[3];
      lsr[(wid * 4 + h) * 32 + mi * 4 + q] = sv;
    }
  }
  __syncthreads();

  // cross-wave (wcN) reduction: 256 rows, one atomic each
  if (tid < 256) {
    const int wrM_r = tid >> 7, within = tid & 127;
    const int mi = within >> 4, h_r = (within >> 2) & 3, j_r = within & 3;
    const int idx = mi * 4 + j_r;
    float v = lsr[((wrM_r * 4 + 0) * 4 + h_r) * 32 + idx] +
              lsr[((wrM_r * 4 + 1) * 4 + h_r) * 32 + idx] +
              lsr[((wrM_r * 4 + 2) * 4 + h_r) * 32 + idx] +
              lsr[((wrM_r * 4 + 3) * 4 + h_r) * 32 + idx];
    atomicAdd(&out[rowA + tid], v * INV_DNT);
  }
}

extern "C" void kernel_launch(void* const* d_in, const int* in_sizes, int n_in,
                              void* d_out, int out_size, void* d_ws, size_t ws_size,
                              hipStream_t stream) {
  const float* src = (const float*)d_in[0];
  const float* tgt = (const float*)d_in[1];
  const int* ssec = (const int*)d_in[2];
  const int* tsec = (const int*)d_in[3];
  float* out = (float*)d_out;
  char* ws = (char*)d_ws;

  hipMemsetAsync(out, 0, (size_t)2 * NS * sizeof(float), stream);
  prep_kernel<<<1024, 256, 0, stream>>>(src, tgt, ws);
  gram_kernel<<<1024, 512, 0, stream>>>(ws, ssec, tsec, out);
}

// Round 6
// 94.618 us; speedup vs baseline: 1.1753x; 1.1753x over previous
//
#include <hip/hip_runtime.h>
#include <stdint.h>
#include <stddef.h>

#define NS 8192
#define NT 8192
#define DD 512
#define QS 32.0f                                 // quant scale: q = rint(32*x)
#define INV_S2 (1.0f / (QS * QS))                // 1/1024
#define INV_DNT (1.0f / ((float)DD * (float)NT))
#define INV_NT  (1.0f / (float)NT)

typedef __attribute__((ext_vector_type(4))) int i32x4;
typedef __attribute__((ext_vector_type(16))) int i32x16;

// ---- workspace layout (bytes) ----
#define WS_A    ((size_t)0)                  // NS*DD i8
#define WS_B    (WS_A + (size_t)NS * DD)     // NT*DD i8
#define WS_SQS  (WS_B + (size_t)NT * DD)     // NS f32 raw row sumsq (exact fp32)
#define WS_SQT  (WS_SQS + (size_t)NS * 4)    // NT f32

__device__ __forceinline__ void gload16(const void* g, void* l) {
  __builtin_amdgcn_global_load_lds(
      (const __attribute__((address_space(1))) unsigned int*)g,
      (__attribute__((address_space(3))) unsigned int*)l, 16, 0, 0);
}

// ============================================================================
// prep: fp32 -> i8 RTN quantization (scale 32, clamp +-127) + exact fp32 row
// sum-of-squares.  1024 blocks x 256 thr; wave handles one row per iter.
// ============================================================================
__global__ __launch_bounds__(256) void prep_kernel(
    const float* __restrict__ src, const float* __restrict__ tgt,
    char* __restrict__ ws) {
  const int tid = threadIdx.x, wid = tid >> 6, lane = tid & 63;
  char* Ai8 = ws + WS_A;
  char* Bi8 = ws + WS_B;
  float* sqs = (float*)(ws + WS_SQS);
  float* sqt = (float*)(ws + WS_SQT);

#pragma unroll
  for (int it = 0; it < 4; ++it) {
    const int row = blockIdx.x * 4 + wid + it * 4096;   // 0..16383
    const bool isT = row >= NS;
    const int r = isT ? row - NS : row;
    const float* in = (isT ? tgt : src) + (size_t)r * DD;
    const float4* rp = (const float4*)in;
    float4 v0 = rp[lane * 2], v1 = rp[lane * 2 + 1];
    float x[8] = {v0.x, v0.y, v0.z, v0.w, v1.x, v1.y, v1.z, v1.w};
    float ss = 0.f;
    int q[8];
#pragma unroll
    for (int j = 0; j < 8; ++j) {
      ss += x[j] * x[j];
      int qi = __float2int_rn(x[j] * QS);           // RTN, unbiased
      q[j] = min(127, max(-127, qi));
    }
    const int lo = (q[0] & 255) | ((q[1] & 255) << 8) |
                   ((q[2] & 255) << 16) | ((q[3] & 255) << 24);
    const int hi = (q[4] & 255) | ((q[5] & 255) << 8) |
                   ((q[6] & 255) << 16) | ((q[7] & 255) << 24);
    *(int2*)((isT ? Bi8 : Ai8) + (size_t)r * DD + lane * 8) = make_int2(lo, hi);
#pragma unroll
    for (int off = 32; off >= 1; off >>= 1) ss += __shfl_xor(ss, off, 64);
    if (lane == 0) (isT ? sqt : sqs)[r] = ss;
  }
}

// ============================================================================
// gram (i8): m97-class 128x128 tile, BK=64, 4 waves (2x2), per-wave 64x64 via
// 2x2 frags of mfma_i32_32x32x32_i8.  Single-buffered LDS (16KB), compiler-
// scheduled barriers, 2 blocks/CU co-resident (TLP does the overlap).
// LDS swizzle: phys byte-in-row = logical ^ (((row>>1)&3)<<4)  (64B i8 rows)
// -> uniform bank load on both ds_read_b128 and staging writes.
// Fused epilogue: loss_s (same-sec sum of raw d2) + hinge (never fires here).
// ============================================================================
__global__ __launch_bounds__(256, 2) void gram_kernel(
    const char* __restrict__ ws, const int* __restrict__ ssec,
    const int* __restrict__ tsec, float* __restrict__ out) {
  __shared__ __align__(16) char As[8192];      // 128 x 64B
  __shared__ __align__(16) char Bs[8192];
  __shared__ float ls_red[2][128];
  __shared__ float sq_l[128];
  __shared__ int sec_l[128];

  const float* sqs = (const float*)(ws + WS_SQS);
  const float* sqt = (const float*)(ws + WS_SQT);

  // XCD map: xcd owns 8 m-tiles; n outer -> B-tile reused across the 8 m's.
  const int lin = blockIdx.x;                  // 4096 = 64x64 tiles
  const int xcd = lin & 7, ii = lin >> 3;
  const int m_blk = xcd * 8 + (ii & 7);
  const int n_blk = ii >> 3;
  const int rowA = m_blk * 128, rowB = n_blk * 128;

  const int tid = threadIdx.x, wid = tid >> 6, lane = tid & 63;
  const int wr = wid >> 1, wc = wid & 1;
  const int lh = lane >> 5;                    // lane half (k-half / row-half)

  // ---- staging addresses: 2 chunks each for A and B per thread ----
  const char* aSrc[2];
  const char* bSrc[2];
  int ldsDst[2];
#pragma unroll
  for (int ih = 0; ih < 2; ++ih) {
    const int o = ih * 4096 + tid * 16;        // linear phys byte in tile
    const int row_p = o >> 6;
    const int bl = (o & 63) ^ (((row_p >> 1) & 3) << 4);  // logical byte-in-row
    ldsDst[ih] = ih * 4096 + wid * 1024;       // wave-uniform LDS base
    aSrc[ih] = ws + WS_A + (size_t)(rowA + row_p) * DD + bl;
    bSrc[ih] = ws + WS_B + (size_t)(rowB + row_p) * DD + bl;
  }

  // ---- fragment read offsets ----
  // a[mi][kk]: row r = wr*64+mi*32+(lane&31); logical byte = kk*32 + lh*16
  int aOff[2][2], bOff[2][2];
#pragma unroll
  for (int mi = 0; mi < 2; ++mi)
#pragma unroll
    for (int kk = 0; kk < 2; ++kk) {
      const int l = kk * 32 + lh * 16;
      const int ra = wr * 64 + mi * 32 + (lane & 31);
      aOff[mi][kk] = ra * 64 + (l ^ (((ra >> 1) & 3) << 4));
      const int rb = wc * 64 + mi * 32 + (lane & 31);
      bOff[mi][kk] = rb * 64 + (l ^ (((rb >> 1) & 3) << 4));
    }

  i32x16 acc[2][2];
#pragma unroll
  for (int mi = 0; mi < 2; ++mi)
#pragma unroll
    for (int ni = 0; ni < 2; ++ni)
#pragma unroll
      for (int j = 0; j < 16; ++j) acc[mi][ni][j] = 0;

  // ---- main loop: 8 K-tiles of 64 ----
  for (int t = 0; t < 8; ++t) {
    const size_t k0 = (size_t)t * 64;
    gload16(aSrc[0] + k0, &As[ldsDst[0]]);
    gload16(aSrc[1] + k0, &As[ldsDst[1]]);
    gload16(bSrc[0] + k0, &Bs[ldsDst[0]]);
    gload16(bSrc[1] + k0, &Bs[ldsDst[1]]);
    __syncthreads();                           // drains vmcnt (m97 structure)

    i32x4 a[2][2], b[2][2];
#pragma unroll
    for (int mi = 0; mi < 2; ++mi)
#pragma unroll
      for (int kk = 0; kk < 2; ++kk) {
        a[mi][kk] = *(const i32x4*)&As[aOff[mi][kk]];
        b[mi][kk] = *(const i32x4*)&Bs[bOff[mi][kk]];
      }
#pragma unroll
    for (int kk = 0; kk < 2; ++kk)
#pragma unroll
      for (int mi = 0; mi < 2; ++mi)
#pragma unroll
        for (int ni = 0; ni < 2; ++ni)
          acc[mi][ni] = __builtin_amdgcn_mfma_i32_32x32x32_i8(
              a[mi][kk], b[ni][kk], acc[mi][ni], 0, 0, 0);
    __syncthreads();
  }

  // ---- epilogue ----
  // C/D 32x32 layout: col = lane&31, row_in_frag = (reg&3)+8*(reg>>2)+4*lh
  if (tid < 128) {
    sq_l[tid] = sqs[rowA + tid];
    sec_l[tid] = ssec[rowA + tid];
  }
  __syncthreads();

  float sqc[2];
  int tc[2];
#pragma unroll
  for (int ni = 0; ni < 2; ++ni) {
    const int gcol = rowB + wc * 64 + ni * 32 + (lane & 31);
    sqc[ni] = sqt[gcol];
    tc[ni] = tsec[gcol];
  }

#pragma unroll
  for (int mi = 0; mi < 2; ++mi) {
#pragma unroll
    for (int reg = 0; reg < 16; ++reg) {
      const int rowin = (reg & 3) + 8 * (reg >> 2) + 4 * lh;
      const int lrow = wr * 64 + mi * 32 + rowin;     // 0..127
      const float sqr = sq_l[lrow];
      const int sc = sec_l[lrow];
      float v = 0.f;
#pragma unroll
      for (int ni = 0; ni < 2; ++ni) {
        const float g = (float)acc[mi][ni][reg] * INV_S2;
        const float d2r = sqr + sqc[ni] - 2.f * g;
        if (sc == tc[ni]) {
          v += fmaxf(d2r, 0.f);
        } else if (d2r < 128.f) {            // margin^2 * D; hinge (rare)
          const float d = sqrtf(fmaxf(d2r, 0.f) * (1.f / (float)DD));
          const float hh = 0.5f - d;
          atomicAdd(&out[NS + rowA + lrow], hh * hh * INV_NT);
        }
      }
      // reduce across the 32 cols (lanes of this half-wave)
      v += __shfl_xor(v, 1, 64);
      v += __shfl_xor(v, 2, 64);
      v += __shfl_xor(v, 4, 64);
      v += __shfl_xor(v, 8, 64);
      v += __shfl_xor(v, 16, 64);
      if ((lane & 31) == rowin) ls_red[wc][lrow] = v;
    }
  }
  __syncthreads();

  if (tid < 128)
    atomicAdd(&out[rowA + tid], (ls_red[0][tid] + ls_red[1][tid]) * INV_DNT);
}

extern "C" void kernel_launch(void* const* d_in, const int* in_sizes, int n_in,
                              void* d_out, int out_size, void* d_ws, size_t ws_size,
                              hipStream_t stream) {
  const float* src = (const float*)d_in[0];
  const float* tgt = (const float*)d_in[1];
  const int* ssec = (const int*)d_in[2];
  const int* tsec = (const int*)d_in[3];
  float* out = (float*)d_out;
  char* ws = (char*)d_ws;

  hipMemsetAsync(out, 0, (size_t)2 * NS * sizeof(float), stream);
  prep_kernel<<<1024, 256, 0, stream>>>(src, tgt, ws);
  gram_kernel<<<4096, 256, 0, stream>>>(ws, ssec, tsec, out);
}

// Round 7
// 86.738 us; speedup vs baseline: 1.2821x; 1.0908x over previous
//
#include <hip/hip_runtime.h>
#include <stdint.h>
#include <stddef.h>

#define NS 8192
#define NT 8192
#define DD 512
#define NSEC 6
#define QS 32.0f                                 // quant scale: q = rint(32*x)
#define INV_S2 (1.0f / (QS * QS))                // 1/1024
#define INV_DNT (1.0f / ((float)DD * (float)NT))
#define INV_NT  (1.0f / (float)NT)

typedef __attribute__((ext_vector_type(4))) int i32x4;
typedef __attribute__((ext_vector_type(16))) int i32x16;

// ---- workspace layout (bytes) ----
#define WS_A    ((size_t)0)                  // NS*DD i8
#define WS_B    (WS_A + (size_t)NS * DD)     // NT*DD i8
#define WS_SQS  (WS_B + (size_t)NT * DD)     // NS f32 raw row sumsq (exact fp32)
#define WS_SQT  (WS_SQS + (size_t)NS * 4)    // NT f32
#define WS_TS   (WS_SQT + (size_t)NT * 4)    // NSEC*DD f32 per-section target sums
#define WS_CNT  (WS_TS + (size_t)NSEC * DD * 4)  // NSEC f32
#define WS_SSQ  (WS_CNT + NSEC * 4)              // NSEC f32
#define WS_ZEND (WS_SSQ + NSEC * 4)

__device__ __forceinline__ void gload16(const void* g, void* l) {
  __builtin_amdgcn_global_load_lds(
      (const __attribute__((address_space(1))) unsigned int*)g,
      (__attribute__((address_space(3))) unsigned int*)l, 16, 0, 0);
}

// ============================================================================
// prep: fp32 -> i8 RTN quantization (scale 32) + exact fp32 row sum-of-squares
// ============================================================================
__global__ __launch_bounds__(256) void prep_kernel(
    const float* __restrict__ src, const float* __restrict__ tgt,
    char* __restrict__ ws) {
  const int tid = threadIdx.x, wid = tid >> 6, lane = tid & 63;
  char* Ai8 = ws + WS_A;
  char* Bi8 = ws + WS_B;
  float* sqs = (float*)(ws + WS_SQS);
  float* sqt = (float*)(ws + WS_SQT);

#pragma unroll
  for (int it = 0; it < 4; ++it) {
    const int row = blockIdx.x * 4 + wid + it * 4096;   // 0..16383
    const bool isT = row >= NS;
    const int r = isT ? row - NS : row;
    const float* in = (isT ? tgt : src) + (size_t)r * DD;
    const float4* rp = (const float4*)in;
    float4 v0 = rp[lane * 2], v1 = rp[lane * 2 + 1];
    float x[8] = {v0.x, v0.y, v0.z, v0.w, v1.x, v1.y, v1.z, v1.w};
    float ss = 0.f;
    int q[8];
#pragma unroll
    for (int j = 0; j < 8; ++j) {
      ss += x[j] * x[j];
      int qi = __float2int_rn(x[j] * QS);           // RTN, unbiased
      q[j] = min(127, max(-127, qi));
    }
    const int lo = (q[0] & 255) | ((q[1] & 255) << 8) |
                   ((q[2] & 255) << 16) | ((q[3] & 255) << 24);
    const int hi = (q[4] & 255) | ((q[5] & 255) << 8) |
                   ((q[6] & 255) << 16) | ((q[7] & 255) << 24);
    *(int2*)((isT ? Bi8 : Ai8) + (size_t)r * DD + lane * 8) = make_int2(lo, hi);
#pragma unroll
    for (int off = 32; off >= 1; off >>= 1) ss += __shfl_xor(ss, off, 64);
    if (lane == 0) (isT ? sqt : sqs)[r] = ss;
  }
}

// ============================================================================
// tsum: per-section target column-sums tsum[6][512] (+ cnt/ssq per section).
// 64 blocks x 512 thr; block handles 128 rows; thread owns one column d.
// ============================================================================
__global__ __launch_bounds__(512) void tsum_kernel(
    const float* __restrict__ tgt, const int* __restrict__ tsec,
    char* __restrict__ ws) {
  const int d = threadIdx.x;
  const int r0 = blockIdx.x * 128;
  float a[NSEC] = {0.f, 0.f, 0.f, 0.f, 0.f, 0.f};
  for (int r = 0; r < 128; ++r) {
    const int sec = tsec[r0 + r];                   // block-uniform scalar
    const float v = tgt[(size_t)(r0 + r) * DD + d];
#pragma unroll
    for (int c = 0; c < NSEC; ++c) a[c] += (sec == c) ? v : 0.f;
  }
  float* ts = (float*)(ws + WS_TS);
#pragma unroll
  for (int c = 0; c < NSEC; ++c) atomicAdd(&ts[c * DD + d], a[c]);

  // cnt / ssq via wave 0 (2 rows per lane)
  if (threadIdx.x < 64) {
    const float* sqt = (const float*)(ws + WS_SQT);
    float cn[NSEC] = {0, 0, 0, 0, 0, 0}, sq[NSEC] = {0, 0, 0, 0, 0, 0};
#pragma unroll
    for (int i = 0; i < 2; ++i) {
      const int r = r0 + i * 64 + threadIdx.x;
      const int sec = tsec[r];
      const float qv = sqt[r];
#pragma unroll
      for (int c = 0; c < NSEC; ++c) {
        cn[c] += (sec == c) ? 1.f : 0.f;
        sq[c] += (sec == c) ? qv : 0.f;
      }
    }
#pragma unroll
    for (int c = 0; c < NSEC; ++c) {
#pragma unroll
      for (int off = 32; off >= 1; off >>= 1) {
        cn[c] += __shfl_xor(cn[c], off, 64);
        sq[c] += __shfl_xor(sq[c], off, 64);
      }
    }
    if (threadIdx.x == 0) {
      float* cnt = (float*)(ws + WS_CNT);
      float* ssq = (float*)(ws + WS_SSQ);
#pragma unroll
      for (int c = 0; c < NSEC; ++c) {
        atomicAdd(&cnt[c], cn[c]);
        atomicAdd(&ssq[c], sq[c]);
      }
    }
  }
}

// ============================================================================
// ls: exact analytic loss_s per source row (wave per row):
//   out[s] = (cnt[c]*sqs[s] + ssq[c] - 2*<src_s, tsum[c]>) / (D*Nt)
// ============================================================================
__global__ __launch_bounds__(256) void ls_kernel(
    const float* __restrict__ src, const int* __restrict__ ssec,
    const char* __restrict__ ws, float* __restrict__ out) {
  const int tid = threadIdx.x, wid = tid >> 6, lane = tid & 63;
  const int row = blockIdx.x * 4 + wid;
  const float* tsum = (const float*)(ws + WS_TS);
  const float* cnt  = (const float*)(ws + WS_CNT);
  const float* ssq  = (const float*)(ws + WS_SSQ);
  const float* sqs  = (const float*)(ws + WS_SQS);

  const int c = ssec[row];
  const float4* rp = (const float4*)(src + (size_t)row * DD);
  const float4* tp = (const float4*)(tsum + c * DD);
  float4 a0 = rp[lane * 2], a1 = rp[lane * 2 + 1];
  float4 b0 = tp[lane * 2], b1 = tp[lane * 2 + 1];
  float dot = a0.x * b0.x + a0.y * b0.y + a0.z * b0.z + a0.w * b0.w +
              a1.x * b1.x + a1.y * b1.y + a1.z * b1.z + a1.w * b1.w;
#pragma unroll
  for (int off = 32; off >= 1; off >>= 1) dot += __shfl_xor(dot, off, 64);
  if (lane == 0)
    out[row] = (cnt[c] * sqs[row] + ssq[c] - 2.f * dot) * INV_DNT;
}

// ============================================================================
// gram (i8): 128x128 tile, BK=64, 4 waves (2x2), 2x2 frags of 32x32x32_i8.
// 3-buffer LDS pipeline, counted vmcnt(4) (never drains mid-loop), raw
// s_barrier.  Epilogue = hinge DETECTION only (integer max vs conservative
// threshold); cold slow-path recomputes exactly (incl. same-sec clamp fix).
// loss_s handled analytically by ls_kernel.
// ============================================================================
__global__ __launch_bounds__(256, 3) void gram_kernel(
    const char* __restrict__ ws, const int* __restrict__ ssec,
    const int* __restrict__ tsec, float* __restrict__ out) {
  __shared__ __align__(16) char lds[3][16384];   // [buf][A 8KB | B 8KB]

  const float* sqs = (const float*)(ws + WS_SQS);
  const float* sqt = (const float*)(ws + WS_SQT);

  // XCD map: xcd owns 8 m-tiles; n outer -> B-tile reused across the 8 m's.
  const int lin = blockIdx.x;                  // 4096 = 64x64 tiles
  const int xcd = lin & 7, ii = lin >> 3;
  const int m_blk = xcd * 8 + (ii & 7);
  const int n_blk = ii >> 3;
  const int rowA = m_blk * 128, rowB = n_blk * 128;

  const int tid = threadIdx.x, wid = tid >> 6, lane = tid & 63;
  const int wr = wid >> 1, wc = wid & 1;
  const int lh = lane >> 5;

  // ---- staging addresses (2 chunks each for A and B per thread) ----
  const char* aSrc[2];
  const char* bSrc[2];
  int ldsDst[2];
#pragma unroll
  for (int ih = 0; ih < 2; ++ih) {
    const int o = ih * 4096 + tid * 16;        // linear phys byte in 8KB tile
    const int row_p = o >> 6;
    const int bl = (o & 63) ^ (((row_p >> 1) & 3) << 4);  // logical byte-in-row
    ldsDst[ih] = ih * 4096 + wid * 1024;       // wave-uniform LDS base
    aSrc[ih] = ws + WS_A + (size_t)(rowA + row_p) * DD + bl;
    bSrc[ih] = ws + WS_B + (size_t)(rowB + row_p) * DD + bl;
  }

#define STAGE(T, BUF)                                                   \
  {                                                                     \
    gload16(aSrc[0] + (size_t)(T) * 64, &lds[BUF][ldsDst[0]]);          \
    gload16(aSrc[1] + (size_t)(T) * 64, &lds[BUF][ldsDst[1]]);          \
    gload16(bSrc[0] + (size_t)(T) * 64, &lds[BUF][8192 + ldsDst[0]]);   \
    gload16(bSrc[1] + (size_t)(T) * 64, &lds[BUF][8192 + ldsDst[1]]);   \
  }

  // ---- fragment read offsets (phys = logical ^ (((row>>1)&3)<<4)) ----
  int aOff[2][2], bOff[2][2];
#pragma unroll
  for (int mi = 0; mi < 2; ++mi)
#pragma unroll
    for (int kk = 0; kk < 2; ++kk) {
      const int l = kk * 32 + lh * 16;
      const int ra = wr * 64 + mi * 32 + (lane & 31);
      aOff[mi][kk] = ra * 64 + (l ^ (((ra >> 1) & 3) << 4));
      const int rb = wc * 64 + mi * 32 + (lane & 31);
      bOff[mi][kk] = 8192 + rb * 64 + (l ^ (((rb >> 1) & 3) << 4));
    }

  i32x16 acc[2][2];
#pragma unroll
  for (int mi = 0; mi < 2; ++mi)
#pragma unroll
    for (int ni = 0; ni < 2; ++ni)
#pragma unroll
      for (int j = 0; j < 16; ++j) acc[mi][ni][j] = 0;

  // ---- prologue: stage tiles 0,1; wait tile 0 (4 of 8 retired) ----
  STAGE(0, 0)
  STAGE(1, 1)
  asm volatile("s_waitcnt vmcnt(4)" ::: "memory");
  __builtin_amdgcn_sched_barrier(0);
  __builtin_amdgcn_s_barrier();

#pragma unroll
  for (int t = 0; t < 8; ++t) {
    const int cur = t % 3;
    if (t + 2 < 8) STAGE(t + 2, (t + 2) % 3)

    i32x4 a[2][2], b[2][2];
#pragma unroll
    for (int mi = 0; mi < 2; ++mi)
#pragma unroll
      for (int kk = 0; kk < 2; ++kk) {
        a[mi][kk] = *(const i32x4*)&lds[cur][aOff[mi][kk]];
        b[mi][kk] = *(const i32x4*)&lds[cur][bOff[mi][kk]];
      }
#pragma unroll
    for (int kk = 0; kk < 2; ++kk)
#pragma unroll
      for (int mi = 0; mi < 2; ++mi)
#pragma unroll
        for (int ni = 0; ni < 2; ++ni)
          acc[mi][ni] = __builtin_amdgcn_mfma_i32_32x32x32_i8(
              a[mi][kk], b[ni][kk], acc[mi][ni], 0, 0, 0);

    __builtin_amdgcn_sched_barrier(0);
    if (t + 2 < 8) {
      asm volatile("s_waitcnt vmcnt(4)" ::: "memory");   // tile t+1 landed
    } else if (t == 6) {
      asm volatile("s_waitcnt vmcnt(0)" ::: "memory");   // tile 7 landed
    }
    __builtin_amdgcn_sched_barrier(0);
    if (t < 7) __builtin_amdgcn_s_barrier();
  }
#undef STAGE

  // ---- epilogue: hinge detection only (loss_s is analytic elsewhere) ----
  // C/D 32x32 layout: col = lane&31, row_in_frag = (reg&3)+8*(reg>>2)+4*lh
  const int colc = lane & 31;
  float sqc[2];
#pragma unroll
  for (int ni = 0; ni < 2; ++ni)
    sqc[ni] = sqt[rowB + wc * 64 + ni * 32 + colc];

  float smin = sqs[rowA + wr * 64 + lane];       // wave-min of row sumsq
#pragma unroll
  for (int off = 32; off >= 1; off >>= 1)
    smin = fminf(smin, __shfl_xor(smin, off, 64));

  // fire if g_int > (sqr + sqc - 128)*512 for ANY row; conservative via smin
  int thr[2];
#pragma unroll
  for (int ni = 0; ni < 2; ++ni)
    thr[ni] = (int)((smin + sqc[ni] - 129.0f) * 512.0f);

  int mx0 = (int)0x80000000, mx1 = (int)0x80000000;
#pragma unroll
  for (int mi = 0; mi < 2; ++mi)
#pragma unroll
    for (int j = 0; j < 16; ++j) {
      mx0 = max(mx0, acc[mi][0][j]);
      mx1 = max(mx1, acc[mi][1][j]);
    }

  if (__any((mx0 > thr[0]) || (mx1 > thr[1]))) {   // cold path (~never)
#pragma unroll
    for (int mi = 0; mi < 2; ++mi) {
#pragma unroll
      for (int j = 0; j < 16; ++j) {
        const int rowin = (j & 3) + 8 * (j >> 2) + 4 * lh;
        const int grow = rowA + wr * 64 + mi * 32 + rowin;
        const float sqr = sqs[grow];
        const int sc = ssec[grow];
#pragma unroll
        for (int ni = 0; ni < 2; ++ni) {
          const int gcol = rowB + wc * 64 + ni * 32 + colc;
          const float d2r =
              sqr + sqc[ni] - 2.f * (float)acc[mi][ni][j] * INV_S2;
          if (d2r < 128.f) {
            if (sc != tsec[gcol]) {                 // hinge contribution
              const float d = sqrtf(fmaxf(d2r, 0.f) * (1.f / (float)DD));
              const float hh = 0.5f - d;
              atomicAdd(&out[NS + grow], hh * hh * INV_NT);
            } else if (d2r < 0.f) {                 // clamp fix for loss_s
              atomicAdd(&out[grow], -d2r * INV_DNT);
            }
          }
        }
      }
    }
  }
}

extern "C" void kernel_launch(void* const* d_in, const int* in_sizes, int n_in,
                              void* d_out, int out_size, void* d_ws, size_t ws_size,
                              hipStream_t stream) {
  const float* src = (const float*)d_in[0];
  const float* tgt = (const float*)d_in[1];
  const int* ssec = (const int*)d_in[2];
  const int* tsec = (const int*)d_in[3];
  float* out = (float*)d_out;
  char* ws = (char*)d_ws;

  hipMemsetAsync(ws + WS_TS, 0, (size_t)(WS_ZEND - WS_TS), stream);
  hipMemsetAsync(out + NS, 0, (size_t)NS * sizeof(float), stream);  // loss_c
  prep_kernel<<<1024, 256, 0, stream>>>(src, tgt, ws);
  tsum_kernel<<<64, 512, 0, stream>>>(tgt, tsec, ws);
  ls_kernel<<<2048, 256, 0, stream>>>(src, ssec, ws, out);
  gram_kernel<<<4096, 256, 0, stream>>>(ws, ssec, tsec, out);
}

// Round 8
// 86.442 us; speedup vs baseline: 1.2865x; 1.0034x over previous
//
#include <hip/hip_runtime.h>
#include <stdint.h>
#include <stddef.h>

#define NS 8192
#define NT 8192
#define DD 512
#define NSEC 6
#define QS 32.0f                                 // quant scale: q = rint(32*x)
#define INV_S2 (1.0f / (QS * QS))                // 1/1024
#define INV_DNT (1.0f / ((float)DD * (float)NT))
#define INV_NT  (1.0f / (float)NT)

typedef __attribute__((ext_vector_type(4))) int i32x4;
typedef __attribute__((ext_vector_type(16))) int i32x16;

// ---- workspace layout (bytes) ----
#define WS_A    ((size_t)0)                  // NS*DD i8
#define WS_B    (WS_A + (size_t)NS * DD)     // NT*DD i8
#define WS_SQS  (WS_B + (size_t)NT * DD)     // NS f32 raw row sumsq (exact fp32)
#define WS_SQT  (WS_SQS + (size_t)NS * 4)    // NT f32
#define WS_TS   (WS_SQT + (size_t)NT * 4)    // NSEC*DD i32 per-section q col-sums
#define WS_CNT  (WS_TS + (size_t)NSEC * DD * 4)  // NSEC f32
#define WS_SSQ  (WS_CNT + NSEC * 4)              // NSEC f32
#define WS_ZEND (WS_SSQ + NSEC * 4)

__device__ __forceinline__ void gload16(const void* g, void* l) {
  __builtin_amdgcn_global_load_lds(
      (const __attribute__((address_space(1))) unsigned int*)g,
      (__attribute__((address_space(3))) unsigned int*)l, 16, 0, 0);
}

// ============================================================================
// prep: fp32 -> i8 RTN quantization (scale 32) + exact fp32 row sum-of-squares
// ============================================================================
__global__ __launch_bounds__(256) void prep_kernel(
    const float* __restrict__ src, const float* __restrict__ tgt,
    char* __restrict__ ws) {
  const int tid = threadIdx.x, wid = tid >> 6, lane = tid & 63;
  char* Ai8 = ws + WS_A;
  char* Bi8 = ws + WS_B;
  float* sqs = (float*)(ws + WS_SQS);
  float* sqt = (float*)(ws + WS_SQT);

#pragma unroll
  for (int it = 0; it < 4; ++it) {
    const int row = blockIdx.x * 4 + wid + it * 4096;   // 0..16383
    const bool isT = row >= NS;
    const int r = isT ? row - NS : row;
    const float* in = (isT ? tgt : src) + (size_t)r * DD;
    const float4* rp = (const float4*)in;
    float4 v0 = rp[lane * 2], v1 = rp[lane * 2 + 1];
    float x[8] = {v0.x, v0.y, v0.z, v0.w, v1.x, v1.y, v1.z, v1.w};
    float ss = 0.f;
    int q[8];
#pragma unroll
    for (int j = 0; j < 8; ++j) {
      ss += x[j] * x[j];
      int qi = __float2int_rn(x[j] * QS);           // RTN, unbiased
      q[j] = min(127, max(-127, qi));
    }
    const int lo = (q[0] & 255) | ((q[1] & 255) << 8) |
                   ((q[2] & 255) << 16) | ((q[3] & 255) << 24);
    const int hi = (q[4] & 255) | ((q[5] & 255) << 8) |
                   ((q[6] & 255) << 16) | ((q[7] & 255) << 24);
    *(int2*)((isT ? Bi8 : Ai8) + (size_t)r * DD + lane * 8) = make_int2(lo, hi);
#pragma unroll
    for (int off = 32; off >= 1; off >>= 1) ss += __shfl_xor(ss, off, 64);
    if (lane == 0) (isT ? sqt : sqs)[r] = ss;
  }
}

// ============================================================================
// tsumq: per-section INTEGER column sums T[6][512] of the quantized targets,
// plus per-section cnt / sum(sqt).  128 blocks x 512 thr (thread = column),
// 64 rows/block, ILP-unrolled; coalesced byte loads of the i8 matrix.
// ============================================================================
__global__ __launch_bounds__(512) void tsumq_kernel(
    const int* __restrict__ tsec, char* __restrict__ ws) {
  const int d = threadIdx.x;
  const int r0 = blockIdx.x * 64;
  const signed char* B = (const signed char*)(ws + WS_B);
  int a[NSEC] = {0, 0, 0, 0, 0, 0};
#pragma unroll 4
  for (int r = 0; r < 64; ++r) {
    const int sec = tsec[r0 + r];
    const int v = (int)B[(size_t)(r0 + r) * DD + d];
#pragma unroll
    for (int c = 0; c < NSEC; ++c) a[c] += (sec == c) ? v : 0;
  }
  int* T = (int*)(ws + WS_TS);
#pragma unroll
  for (int c = 0; c < NSEC; ++c) atomicAdd(&T[c * DD + d], a[c]);

  if (threadIdx.x < 64) {                       // cnt / ssq via wave 0
    const float* sqt = (const float*)(ws + WS_SQT);
    const int r = r0 + threadIdx.x;
    const int sec = tsec[r];
    const float qv = sqt[r];
    float cn[NSEC], sq[NSEC];
#pragma unroll
    for (int c = 0; c < NSEC; ++c) {
      cn[c] = (sec == c) ? 1.f : 0.f;
      sq[c] = (sec == c) ? qv : 0.f;
    }
#pragma unroll
    for (int c = 0; c < NSEC; ++c) {
#pragma unroll
      for (int off = 32; off >= 1; off >>= 1) {
        cn[c] += __shfl_xor(cn[c], off, 64);
        sq[c] += __shfl_xor(sq[c], off, 64);
      }
    }
    if (threadIdx.x == 0) {
      float* cnt = (float*)(ws + WS_CNT);
      float* ssq = (float*)(ws + WS_SSQ);
#pragma unroll
      for (int c = 0; c < NSEC; ++c) {
        atomicAdd(&cnt[c], cn[c]);
        atomicAdd(&ssq[c], sq[c]);
      }
    }
  }
}

// ============================================================================
// ls: loss_s per source row via the EXACT integer identity
//   sum_{t same} g_int = q_s . T_c   (T_c = integer col-sum of same-sec q_t)
//   out[s] = (cnt_c*sqs[s] + ssq_c - (q_s.T_c)/512) / (D*Nt)
// wave per row; int dot in registers; one write per row.
// ============================================================================
__global__ __launch_bounds__(256) void ls_kernel(
    const int* __restrict__ ssec, const char* __restrict__ ws,
    float* __restrict__ out) {
  const int tid = threadIdx.x, wid = tid >> 6, lane = tid & 63;
  const int row = blockIdx.x * 4 + wid;
  const int c = ssec[row];
  const signed char* A = (const signed char*)(ws + WS_A);
  const int* T = (const int*)(ws + WS_TS) + c * DD;

  union { int2 v; signed char b[8]; } u;
  u.v = *(const int2*)(A + (size_t)row * DD + lane * 8);
  i32x4 t0 = *(const i32x4*)(T + lane * 8);
  i32x4 t1 = *(const i32x4*)(T + lane * 8 + 4);
  int s = (int)u.b[0] * t0[0] + (int)u.b[1] * t0[1] +
          (int)u.b[2] * t0[2] + (int)u.b[3] * t0[3] +
          (int)u.b[4] * t1[0] + (int)u.b[5] * t1[1] +
          (int)u.b[6] * t1[2] + (int)u.b[7] * t1[3];
#pragma unroll
  for (int off = 32; off >= 1; off >>= 1) s += __shfl_xor(s, off, 64);

  if (lane == 0) {
    const float* cnt = (const float*)(ws + WS_CNT);
    const float* ssq = (const float*)(ws + WS_SSQ);
    const float* sqs = (const float*)(ws + WS_SQS);
    out[row] = (cnt[c] * sqs[row] + ssq[c] - (float)s * (1.0f / 512.0f)) *
               INV_DNT;
  }
}

// ============================================================================
// gram (i8): block 128x256, BK=64, 4 waves (2M x 2N), per-wave 64x128 =
// 2x4 frags of mfma_i32_32x32x32_i8 -> 12 ds_read_b128 per 16 MFMA (LDS pipe
// balanced with MFMA pipe).  3-buffer LDS pipeline, counted vmcnt(6).
// Epilogue = hinge DETECTION only (integer max vs conservative threshold);
// cold path recomputes exactly.  No LDS use after the main loop.
// ============================================================================
__global__ __launch_bounds__(256, 2) void gram_kernel(
    const char* __restrict__ ws, const int* __restrict__ ssec,
    const int* __restrict__ tsec, float* __restrict__ out) {
  __shared__ __align__(16) char lds[3][24576];   // [buf][A 8KB | B 16KB]

  const float* sqs = (const float*)(ws + WS_SQS);
  const float* sqt = (const float*)(ws + WS_SQT);

  // XCD map: xcd owns 8 consecutive m-blocks; n outer (B-tile L2-shared).
  const int lin = blockIdx.x;                  // 2048 = 64(m) x 32(n)
  const int xcd = lin & 7, ii = lin >> 3;
  const int m_blk = xcd * 8 + (ii & 7);
  const int n_blk = ii >> 3;
  const int rowA = m_blk * 128, rowB = n_blk * 256;

  const int tid = threadIdx.x, wid = tid >> 6, lane = tid & 63;
  const int wr = wid >> 1, wc = wid & 1;       // 2M x 2N wave grid
  const int lh = lane >> 5;

  // ---- staging: A 2 chunks, B 4 chunks per thread (16B each) ----
  const char* aSrc[2];
  const char* bSrc[4];
  int aDst[2], bDst[4];
#pragma unroll
  for (int ih = 0; ih < 2; ++ih) {
    const int o = ih * 4096 + tid * 16;
    const int row_p = o >> 6;
    const int bl = (o & 63) ^ (((row_p >> 1) & 3) << 4);
    aDst[ih] = ih * 4096 + wid * 1024;
    aSrc[ih] = ws + WS_A + (size_t)(rowA + row_p) * DD + bl;
  }
#pragma unroll
  for (int ih = 0; ih < 4; ++ih) {
    const int o = ih * 4096 + tid * 16;
    const int row_p = o >> 6;
    const int bl = (o & 63) ^ (((row_p >> 1) & 3) << 4);
    bDst[ih] = 8192 + ih * 4096 + wid * 1024;
    bSrc[ih] = ws + WS_B + (size_t)(rowB + row_p) * DD + bl;
  }

#define STAGE(T, BUF)                                             \
  {                                                               \
    gload16(aSrc[0] + (size_t)(T) * 64, &lds[BUF][aDst[0]]);      \
    gload16(aSrc[1] + (size_t)(T) * 64, &lds[BUF][aDst[1]]);      \
    gload16(bSrc[0] + (size_t)(T) * 64, &lds[BUF][bDst[0]]);      \
    gload16(bSrc[1] + (size_t)(T) * 64, &lds[BUF][bDst[1]]);      \
    gload16(bSrc[2] + (size_t)(T) * 64, &lds[BUF][bDst[2]]);      \
    gload16(bSrc[3] + (size_t)(T) * 64, &lds[BUF][bDst[3]]);      \
  }

  // ---- fragment read offsets (phys = logical ^ (((row>>1)&3)<<4)) ----
  int aOff[2][2], bOff[4][2];
#pragma unroll
  for (int kk = 0; kk < 2; ++kk) {
    const int l = kk * 32 + lh * 16;
#pragma unroll
    for (int mi = 0; mi < 2; ++mi) {
      const int ra = wr * 64 + mi * 32 + (lane & 31);
      aOff[mi][kk] = ra * 64 + (l ^ (((ra >> 1) & 3) << 4));
    }
#pragma unroll
    for (int ni = 0; ni < 4; ++ni) {
      const int rb = wc * 128 + ni * 32 + (lane & 31);
      bOff[ni][kk] = 8192 + rb * 64 + (l ^ (((rb >> 1) & 3) << 4));
    }
  }

  i32x16 acc[2][4];
#pragma unroll
  for (int mi = 0; mi < 2; ++mi)
#pragma unroll
    for (int ni = 0; ni < 4; ++ni)
#pragma unroll
      for (int j = 0; j < 16; ++j) acc[mi][ni][j] = 0;

  // ---- prologue: stage tiles 0,1; wait tile 0 (6 newest outstanding) ----
  STAGE(0, 0)
  STAGE(1, 1)
  asm volatile("s_waitcnt vmcnt(6)" ::: "memory");
  __builtin_amdgcn_sched_barrier(0);
  __builtin_amdgcn_s_barrier();

#pragma unroll
  for (int t = 0; t < 8; ++t) {
    const int cur = t % 3;
    if (t + 2 < 8) STAGE(t + 2, (t + 2) % 3)

    i32x4 a[2][2], b[4][2];
#pragma unroll
    for (int kk = 0; kk < 2; ++kk) {
#pragma unroll
      for (int mi = 0; mi < 2; ++mi)
        a[mi][kk] = *(const i32x4*)&lds[cur][aOff[mi][kk]];
#pragma unroll
      for (int ni = 0; ni < 4; ++ni)
        b[ni][kk] = *(const i32x4*)&lds[cur][bOff[ni][kk]];
    }
#pragma unroll
    for (int kk = 0; kk < 2; ++kk)
#pragma unroll
      for (int mi = 0; mi < 2; ++mi)
#pragma unroll
        for (int ni = 0; ni < 4; ++ni)
          acc[mi][ni] = __builtin_amdgcn_mfma_i32_32x32x32_i8(
              a[mi][kk], b[ni][kk], acc[mi][ni], 0, 0, 0);

    __builtin_amdgcn_sched_barrier(0);
    if (t + 2 < 8) {
      asm volatile("s_waitcnt vmcnt(6)" ::: "memory");   // tile t+1 landed
    } else if (t == 6) {
      asm volatile("s_waitcnt vmcnt(0)" ::: "memory");   // tile 7 landed
    }
    __builtin_amdgcn_sched_barrier(0);
    if (t < 7) __builtin_amdgcn_s_barrier();
  }
#undef STAGE

  // ---- epilogue: hinge detection only ----
  // C/D 32x32 layout: col = lane&31, row_in_frag = (j&3)+8*(j>>2)+4*lh
  const int colc = lane & 31;
  float sqc[4];
#pragma unroll
  for (int ni = 0; ni < 4; ++ni)
    sqc[ni] = sqt[rowB + wc * 128 + ni * 32 + colc];

  float smin = sqs[rowA + wr * 64 + lane];       // wave-min of its 64 rows
#pragma unroll
  for (int off = 32; off >= 1; off >>= 1)
    smin = fminf(smin, __shfl_xor(smin, off, 64));

  int thr[4];
#pragma unroll
  for (int ni = 0; ni < 4; ++ni)
    thr[ni] = (int)((smin + sqc[ni] - 129.0f) * 512.0f);

  int mx[4] = {(int)0x80000000, (int)0x80000000,
               (int)0x80000000, (int)0x80000000};
#pragma unroll
  for (int mi = 0; mi < 2; ++mi)
#pragma unroll
    for (int ni = 0; ni < 4; ++ni)
#pragma unroll
      for (int j = 0; j < 16; ++j) mx[ni] = max(mx[ni], acc[mi][ni][j]);

  const bool fire = (mx[0] > thr[0]) || (mx[1] > thr[1]) ||
                    (mx[2] > thr[2]) || (mx[3] > thr[3]);
  if (__any(fire)) {                              // cold path (~never)
#pragma unroll
    for (int mi = 0; mi < 2; ++mi) {
#pragma unroll
      for (int j = 0; j < 16; ++j) {
        const int rowin = (j & 3) + 8 * (j >> 2) + 4 * lh;
        const int grow = rowA + wr * 64 + mi * 32 + rowin;
        const float sqr = sqs[grow];
        const int sc = ssec[grow];
#pragma unroll
        for (int ni = 0; ni < 4; ++ni) {
          const int gcol = rowB + wc * 128 + ni * 32 + colc;
          const float d2r =
              sqr + sqc[ni] - 2.f * (float)acc[mi][ni][j] * INV_S2;
          if (d2r < 128.f) {
            if (sc != tsec[gcol]) {                 // hinge contribution
              const float d = sqrtf(fmaxf(d2r, 0.f) * (1.f / (float)DD));
              const float hh = 0.5f - d;
              atomicAdd(&out[NS + grow], hh * hh * INV_NT);
            } else if (d2r < 0.f) {                 // clamp fix for loss_s
              atomicAdd(&out[grow], -d2r * INV_DNT);
            }
          }
        }
      }
    }
  }
}

extern "C" void kernel_launch(void* const* d_in, const int* in_sizes, int n_in,
                              void* d_out, int out_size, void* d_ws, size_t ws_size,
                              hipStream_t stream) {
  const float* src = (const float*)d_in[0];
  const float* tgt = (const float*)d_in[1];
  const int* ssec = (const int*)d_in[2];
  const int* tsec = (const int*)d_in[3];
  float* out = (float*)d_out;
  char* ws = (char*)d_ws;

  hipMemsetAsync(ws + WS_TS, 0, (size_t)(WS_ZEND - WS_TS), stream);
  hipMemsetAsync(out + NS, 0, (size_t)NS * sizeof(float), stream);  // loss_c
  prep_kernel<<<1024, 256, 0, stream>>>(src, tgt, ws);
  tsumq_kernel<<<128, 512, 0, stream>>>(tsec, ws);
  ls_kernel<<<2048, 256, 0, stream>>>(ssec, ws, out);
  gram_kernel<<<2048, 256, 0, stream>>>(ws, ssec, tsec, out);
}

// Round 9
// 79.677 us; speedup vs baseline: 1.3957x; 1.0849x over previous
//
#include <hip/hip_runtime.h>
#include <stdint.h>
#include <stddef.h>

#define NS 8192
#define NT 8192
#define DD 512
#define NSEC 6
#define QS 32.0f                                 // quant scale: q = rint(32*x)
#define INV_S2 (1.0f / (QS * QS))                // 1/1024
#define INV_DNT (1.0f / ((float)DD * (float)NT))
#define INV_NT  (1.0f / (float)NT)

typedef __attribute__((ext_vector_type(4))) int i32x4;
typedef __attribute__((ext_vector_type(16))) int i32x16;

// ---- workspace layout (bytes) ----
#define WS_A    ((size_t)0)                  // NS*DD i8
#define WS_B    (WS_A + (size_t)NS * DD)     // NT*DD i8
#define WS_SQS  (WS_B + (size_t)NT * DD)     // NS f32 raw row sumsq (exact fp32)
#define WS_SQT  (WS_SQS + (size_t)NS * 4)    // NT f32
#define WS_TS   (WS_SQT + (size_t)NT * 4)    // NSEC*DD i32 per-section q col-sums
#define WS_CNT  (WS_TS + (size_t)NSEC * DD * 4)  // NSEC f32
#define WS_SSQ  (WS_CNT + NSEC * 4)              // NSEC f32
#define WS_ZEND (WS_SSQ + NSEC * 4)

__device__ __forceinline__ void gload16(const void* g, void* l) {
  __builtin_amdgcn_global_load_lds(
      (const __attribute__((address_space(1))) unsigned int*)g,
      (__attribute__((address_space(3))) unsigned int*)l, 16, 0, 0);
}

// ============================================================================
// prep: fp32 -> i8 RTN quantization (scale 32) + exact fp32 row sum-of-squares.
// Block 0 additionally zeroes the TS/CNT/SSQ accumulator region (12,336 B) --
// no other prep block touches it and tsumq is stream-ordered after prep, so
// this replaces the hipMemsetAsync dispatch.
// ============================================================================
__global__ __launch_bounds__(256) void prep_kernel(
    const float* __restrict__ src, const float* __restrict__ tgt,
    char* __restrict__ ws) {
  const int tid = threadIdx.x, wid = tid >> 6, lane = tid & 63;
  char* Ai8 = ws + WS_A;
  char* Bi8 = ws + WS_B;
  float* sqs = (float*)(ws + WS_SQS);
  float* sqt = (float*)(ws + WS_SQT);

  if (blockIdx.x == 0) {                     // zero TS/CNT/SSQ (3084 dwords)
    int* Z = (int*)(ws + WS_TS);
    for (int i = tid; i < (int)((WS_ZEND - WS_TS) >> 2); i += 256) Z[i] = 0;
  }

#pragma unroll
  for (int it = 0; it < 4; ++it) {
    const int row = blockIdx.x * 4 + wid + it * 4096;   // 0..16383
    const bool isT = row >= NS;
    const int r = isT ? row - NS : row;
    const float* in = (isT ? tgt : src) + (size_t)r * DD;
    const float4* rp = (const float4*)in;
    float4 v0 = rp[lane * 2], v1 = rp[lane * 2 + 1];
    float x[8] = {v0.x, v0.y, v0.z, v0.w, v1.x, v1.y, v1.z, v1.w};
    float ss = 0.f;
    int q[8];
#pragma unroll
    for (int j = 0; j < 8; ++j) {
      ss += x[j] * x[j];
      int qi = __float2int_rn(x[j] * QS);           // RTN, unbiased
      q[j] = min(127, max(-127, qi));
    }
    const int lo = (q[0] & 255) | ((q[1] & 255) << 8) |
                   ((q[2] & 255) << 16) | ((q[3] & 255) << 24);
    const int hi = (q[4] & 255) | ((q[5] & 255) << 8) |
                   ((q[6] & 255) << 16) | ((q[7] & 255) << 24);
    *(int2*)((isT ? Bi8 : Ai8) + (size_t)r * DD + lane * 8) = make_int2(lo, hi);
#pragma unroll
    for (int off = 32; off >= 1; off >>= 1) ss += __shfl_xor(ss, off, 64);
    if (lane == 0) (isT ? sqt : sqs)[r] = ss;
  }
}

// ============================================================================
// tsumq: per-section INTEGER column sums T[6][512] of the quantized targets,
// plus per-section cnt / sum(sqt).  128 blocks x 512 thr (thread = column).
// ============================================================================
__global__ __launch_bounds__(512) void tsumq_kernel(
    const int* __restrict__ tsec, char* __restrict__ ws) {
  const int d = threadIdx.x;
  const int r0 = blockIdx.x * 64;
  const signed char* B = (const signed char*)(ws + WS_B);
  int a[NSEC] = {0, 0, 0, 0, 0, 0};
#pragma unroll 4
  for (int r = 0; r < 64; ++r) {
    const int sec = tsec[r0 + r];
    const int v = (int)B[(size_t)(r0 + r) * DD + d];
#pragma unroll
    for (int c = 0; c < NSEC; ++c) a[c] += (sec == c) ? v : 0;
  }
  int* T = (int*)(ws + WS_TS);
#pragma unroll
  for (int c = 0; c < NSEC; ++c) atomicAdd(&T[c * DD + d], a[c]);

  if (threadIdx.x < 64) {                       // cnt / ssq via wave 0
    const float* sqt = (const float*)(ws + WS_SQT);
    const int r = r0 + threadIdx.x;
    const int sec = tsec[r];
    const float qv = sqt[r];
    float cn[NSEC], sq[NSEC];
#pragma unroll
    for (int c = 0; c < NSEC; ++c) {
      cn[c] = (sec == c) ? 1.f : 0.f;
      sq[c] = (sec == c) ? qv : 0.f;
    }
#pragma unroll
    for (int c = 0; c < NSEC; ++c) {
#pragma unroll
      for (int off = 32; off >= 1; off >>= 1) {
        cn[c] += __shfl_xor(cn[c], off, 64);
        sq[c] += __shfl_xor(sq[c], off, 64);
      }
    }
    if (threadIdx.x == 0) {
      float* cnt = (float*)(ws + WS_CNT);
      float* ssq = (float*)(ws + WS_SSQ);
#pragma unroll
      for (int c = 0; c < NSEC; ++c) {
        atomicAdd(&cnt[c], cn[c]);
        atomicAdd(&ssq[c], sq[c]);
      }
    }
  }
}

// ============================================================================
// ls: loss_s per source row via the EXACT integer identity
//   sum_{t same} g_int = q_s . T_c;  also zeroes the loss_c half of out
// (replacing the out hipMemsetAsync; gram's cold-path atomics come after).
// ============================================================================
__global__ __launch_bounds__(256) void ls_kernel(
    const int* __restrict__ ssec, const char* __restrict__ ws,
    float* __restrict__ out) {
  const int tid = threadIdx.x, wid = tid >> 6, lane = tid & 63;
  const int row = blockIdx.x * 4 + wid;
  const int c = ssec[row];
  const signed char* A = (const signed char*)(ws + WS_A);
  const int* T = (const int*)(ws + WS_TS) + c * DD;

  union { int2 v; signed char b[8]; } u;
  u.v = *(const int2*)(A + (size_t)row * DD + lane * 8);
  i32x4 t0 = *(const i32x4*)(T + lane * 8);
  i32x4 t1 = *(const i32x4*)(T + lane * 8 + 4);
  int s = (int)u.b[0] * t0[0] + (int)u.b[1] * t0[1] +
          (int)u.b[2] * t0[2] + (int)u.b[3] * t0[3] +
          (int)u.b[4] * t1[0] + (int)u.b[5] * t1[1] +
          (int)u.b[6] * t1[2] + (int)u.b[7] * t1[3];
#pragma unroll
  for (int off = 32; off >= 1; off >>= 1) s += __shfl_xor(s, off, 64);

  if (lane == 0) {
    const float* cnt = (const float*)(ws + WS_CNT);
    const float* ssq = (const float*)(ws + WS_SSQ);
    const float* sqs = (const float*)(ws + WS_SQS);
    out[row] = (cnt[c] * sqs[row] + ssq[c] - (float)s * (1.0f / 512.0f)) *
               INV_DNT;
    out[NS + row] = 0.f;                        // loss_c accumulator base
  }
}

// ============================================================================
// gram (i8): block 128x256, BK=64, 4 waves (2M x 2N), per-wave 64x128 =
// 2x4 frags of mfma_i32_32x32x32_i8.  3-buffer LDS pipeline, counted
// vmcnt(6).  Epilogue = hinge DETECTION only; cold path recomputes exactly.
// (unchanged from r8 -- this round isolates the memset-dispatch removal)
// ============================================================================
__global__ __launch_bounds__(256, 2) void gram_kernel(
    const char* __restrict__ ws, const int* __restrict__ ssec,
    const int* __restrict__ tsec, float* __restrict__ out) {
  __shared__ __align__(16) char lds[3][24576];   // [buf][A 8KB | B 16KB]

  const float* sqs = (const float*)(ws + WS_SQS);
  const float* sqt = (const float*)(ws + WS_SQT);

  const int lin = blockIdx.x;                  // 2048 = 64(m) x 32(n)
  const int xcd = lin & 7, ii = lin >> 3;
  const int m_blk = xcd * 8 + (ii & 7);
  const int n_blk = ii >> 3;
  const int rowA = m_blk * 128, rowB = n_blk * 256;

  const int tid = threadIdx.x, wid = tid >> 6, lane = tid & 63;
  const int wr = wid >> 1, wc = wid & 1;       // 2M x 2N wave grid
  const int lh = lane >> 5;

  // ---- staging: A 2 chunks, B 4 chunks per thread (16B each) ----
  const char* aSrc[2];
  const char* bSrc[4];
  int aDst[2], bDst[4];
#pragma unroll
  for (int ih = 0; ih < 2; ++ih) {
    const int o = ih * 4096 + tid * 16;
    const int row_p = o >> 6;
    const int bl = (o & 63) ^ (((row_p >> 1) & 3) << 4);
    aDst[ih] = ih * 4096 + wid * 1024;
    aSrc[ih] = ws + WS_A + (size_t)(rowA + row_p) * DD + bl;
  }
#pragma unroll
  for (int ih = 0; ih < 4; ++ih) {
    const int o = ih * 4096 + tid * 16;
    const int row_p = o >> 6;
    const int bl = (o & 63) ^ (((row_p >> 1) & 3) << 4);
    bDst[ih] = 8192 + ih * 4096 + wid * 1024;
    bSrc[ih] = ws + WS_B + (size_t)(rowB + row_p) * DD + bl;
  }

#define STAGE(T, BUF)                                             \
  {                                                               \
    gload16(aSrc[0] + (size_t)(T) * 64, &lds[BUF][aDst[0]]);      \
    gload16(aSrc[1] + (size_t)(T) * 64, &lds[BUF][aDst[1]]);      \
    gload16(bSrc[0] + (size_t)(T) * 64, &lds[BUF][bDst[0]]);      \
    gload16(bSrc[1] + (size_t)(T) * 64, &lds[BUF][bDst[1]]);      \
    gload16(bSrc[2] + (size_t)(T) * 64, &lds[BUF][bDst[2]]);      \
    gload16(bSrc[3] + (size_t)(T) * 64, &lds[BUF][bDst[3]]);      \
  }

  // ---- fragment read offsets (phys = logical ^ (((row>>1)&3)<<4)) ----
  int aOff[2][2], bOff[4][2];
#pragma unroll
  for (int kk = 0; kk < 2; ++kk) {
    const int l = kk * 32 + lh * 16;
#pragma unroll
    for (int mi = 0; mi < 2; ++mi) {
      const int ra = wr * 64 + mi * 32 + (lane & 31);
      aOff[mi][kk] = ra * 64 + (l ^ (((ra >> 1) & 3) << 4));
    }
#pragma unroll
    for (int ni = 0; ni < 4; ++ni) {
      const int rb = wc * 128 + ni * 32 + (lane & 31);
      bOff[ni][kk] = 8192 + rb * 64 + (l ^ (((rb >> 1) & 3) << 4));
    }
  }

  i32x16 acc[2][4];
#pragma unroll
  for (int mi = 0; mi < 2; ++mi)
#pragma unroll
    for (int ni = 0; ni < 4; ++ni)
#pragma unroll
      for (int j = 0; j < 16; ++j) acc[mi][ni][j] = 0;

  // ---- prologue ----
  STAGE(0, 0)
  STAGE(1, 1)
  asm volatile("s_waitcnt vmcnt(6)" ::: "memory");
  __builtin_amdgcn_sched_barrier(0);
  __builtin_amdgcn_s_barrier();

#pragma unroll
  for (int t = 0; t < 8; ++t) {
    const int cur = t % 3;
    if (t + 2 < 8) STAGE(t + 2, (t + 2) % 3)

    i32x4 a[2][2], b[4][2];
#pragma unroll
    for (int kk = 0; kk < 2; ++kk) {
#pragma unroll
      for (int mi = 0; mi < 2; ++mi)
        a[mi][kk] = *(const i32x4*)&lds[cur][aOff[mi][kk]];
#pragma unroll
      for (int ni = 0; ni < 4; ++ni)
        b[ni][kk] = *(const i32x4*)&lds[cur][bOff[ni][kk]];
    }
#pragma unroll
    for (int kk = 0; kk < 2; ++kk)
#pragma unroll
      for (int mi = 0; mi < 2; ++mi)
#pragma unroll
        for (int ni = 0; ni < 4; ++ni)
          acc[mi][ni] = __builtin_amdgcn_mfma_i32_32x32x32_i8(
              a[mi][kk], b[ni][kk], acc[mi][ni], 0, 0, 0);

    __builtin_amdgcn_sched_barrier(0);
    if (t + 2 < 8) {
      asm volatile("s_waitcnt vmcnt(6)" ::: "memory");   // tile t+1 landed
    } else if (t == 6) {
      asm volatile("s_waitcnt vmcnt(0)" ::: "memory");   // tile 7 landed
    }
    __builtin_amdgcn_sched_barrier(0);
    if (t < 7) __builtin_amdgcn_s_barrier();
  }
#undef STAGE

  // ---- epilogue: hinge detection only ----
  const int colc = lane & 31;
  float sqc[4];
#pragma unroll
  for (int ni = 0; ni < 4; ++ni)
    sqc[ni] = sqt[rowB + wc * 128 + ni * 32 + colc];

  float smin = sqs[rowA + wr * 64 + lane];       // wave-min of its 64 rows
#pragma unroll
  for (int off = 32; off >= 1; off >>= 1)
    smin = fminf(smin, __shfl_xor(smin, off, 64));

  int thr[4];
#pragma unroll
  for (int ni = 0; ni < 4; ++ni)
    thr[ni] = (int)((smin + sqc[ni] - 129.0f) * 512.0f);

  int mx[4] = {(int)0x80000000, (int)0x80000000,
               (int)0x80000000, (int)0x80000000};
#pragma unroll
  for (int mi = 0; mi < 2; ++mi)
#pragma unroll
    for (int ni = 0; ni < 4; ++ni)
#pragma unroll
      for (int j = 0; j < 16; ++j) mx[ni] = max(mx[ni], acc[mi][ni][j]);

  const bool fire = (mx[0] > thr[0]) || (mx[1] > thr[1]) ||
                    (mx[2] > thr[2]) || (mx[3] > thr[3]);
  if (__any(fire)) {                              // cold path (~never)
#pragma unroll
    for (int mi = 0; mi < 2; ++mi) {
#pragma unroll
      for (int j = 0; j < 16; ++j) {
        const int rowin = (j & 3) + 8 * (j >> 2) + 4 * lh;
        const int grow = rowA + wr * 64 + mi * 32 + rowin;
        const float sqr = sqs[grow];
        const int sc = ssec[grow];
#pragma unroll
        for (int ni = 0; ni < 4; ++ni) {
          const int gcol = rowB + wc * 128 + ni * 32 + colc;
          const float d2r =
              sqr + sqc[ni] - 2.f * (float)acc[mi][ni][j] * INV_S2;
          if (d2r < 128.f) {
            if (sc != tsec[gcol]) {                 // hinge contribution
              const float d = sqrtf(fmaxf(d2r, 0.f) * (1.f / (float)DD));
              const float hh = 0.5f - d;
              atomicAdd(&out[NS + grow], hh * hh * INV_NT);
            } else if (d2r < 0.f) {                 // clamp fix for loss_s
              atomicAdd(&out[grow], -d2r * INV_DNT);
            }
          }
        }
      }
    }
  }
}

extern "C" void kernel_launch(void* const* d_in, const int* in_sizes, int n_in,
                              void* d_out, int out_size, void* d_ws, size_t ws_size,
                              hipStream_t stream) {
  const float* src = (const float*)d_in[0];
  const float* tgt = (const float*)d_in[1];
  const int* ssec = (const int*)d_in[2];
  const int* tsec = (const int*)d_in[3];
  float* out = (float*)d_out;
  char* ws = (char*)d_ws;

  prep_kernel<<<1024, 256, 0, stream>>>(src, tgt, ws);
  tsumq_kernel<<<128, 512, 0, stream>>>(tsec, ws);
  ls_kernel<<<2048, 256, 0, stream>>>(ssec, ws, out);
  gram_kernel<<<2048, 256, 0, stream>>>(ws, ssec, tsec, out);
}